// Round 14
// baseline (3159.645 us; speedup 1.0000x reference)
//
#include <hip/hip_runtime.h>
#include <hip/hip_bf16.h>
#include <stdint.h>

typedef __attribute__((ext_vector_type(4))) float f32x4;
typedef __attribute__((ext_vector_type(8))) short bf16x8;
typedef __attribute__((ext_vector_type(8))) unsigned short us8;
typedef unsigned short u16;
typedef unsigned int u32;
typedef unsigned long long u64;

#define DEV static __device__ __forceinline__

DEV u16 f2b(float f){
  u32 u = __float_as_uint(f);
  u += 0x7fffu + ((u >> 16) & 1u);
  return (u16)(u >> 16);
}
DEV float b2f(u16 h){ return __uint_as_float(((u32)h) << 16); }

// ---------------- zero helper (re-runs every launch: replay-safe) ----------------
__global__ void k_zero(u32* __restrict__ p, int n){
  int i = blockIdx.x*blockDim.x + threadIdx.x;
  if (i < n) p[i] = 0;
}

// ---------------- pad & cast x ----------------
__global__ void k_pad_cast(const float* __restrict__ x, u16* __restrict__ xp){
  int i8 = blockIdx.x * blockDim.x + threadIdx.x;
  int d8 = i8 % 96; int rest = i8 / 96;
  int sp = rest % 262; int b = rest / 262;
  us8 o;
  int s = sp - 3;
  if (s >= 0 && s < 256){
    const float* src = x + ((long)(b*256 + s)*768 + d8*8);
    #pragma unroll
    for (int j=0;j<8;j++) o[j] = f2b(src[j]);
  } else {
    #pragma unroll
    for (int j=0;j<8;j++) o[j] = 0;
  }
  *(us8*)(xp + (long)i8*8) = o;
}

// ---------------- V[d][c][i] ----------------
__global__ void k_build_v(const float* __restrict__ cw3, const float* __restrict__ cw5,
                          const float* __restrict__ cw7, float* __restrict__ V){
  int idx = blockIdx.x * blockDim.x + threadIdx.x;
  if (idx >= 7*768*768) return;
  int d = idx / (768*768); int rem = idx - d*(768*768);
  int c = rem / 768; int i = rem - c*768;
  int dd = d - 3;
  float v = 0.f;
  if (c < 256){ int t = dd + 1; if (t >= 0 && t < 3) v = cw3[((long)c*768 + i)*3 + t]; }
  else if (c < 512){ int t = dd + 2; if (t >= 0 && t < 5) v = cw5[((long)(c-256)*768 + i)*5 + t]; }
  else { int t = dd + 3; v = cw7[((long)(c-512)*768 + i)*7 + t]; }
  V[idx] = v;
}

// ---------------- Weff (K-loop starts at first nonzero channel block per tap) ----------------
__global__ __launch_bounds__(256) void k_weff(
    const float* __restrict__ wxrz, const float* __restrict__ wxn,
    const float* __restrict__ V, u16* __restrict__ wt)
{
  __shared__ float As[16][64];
  __shared__ float Bs[16][64];
  const int t = threadIdx.x;
  const int it = blockIdx.x, jt = blockIdx.y, dlt = blockIdx.z;
  const int add3 = (dlt >= 3) ? dlt - 3 : 3 - dlt;
  const int cstart = (add3 == 3) ? 512 : (add3 == 2) ? 256 : 0;
  const float* Arow = (jt < 12) ? (wxrz + (long)jt*64*768) : (wxn + (long)(jt-12)*64*768);
  const int tx = t & 15, ty = t >> 4;
  const int jA = t >> 2, cqA = (t & 3) * 4;
  const int iB = t & 63, cB = t >> 6;
  float acc[4][4] = {};
  for (int k0 = cstart; k0 < 768; k0 += 16){
    __syncthreads();
    float4 av = *(const float4*)(Arow + (long)jA*768 + k0 + cqA);
    As[cqA+0][jA] = av.x; As[cqA+1][jA] = av.y; As[cqA+2][jA] = av.z; As[cqA+3][jA] = av.w;
    #pragma unroll
    for (int l=0;l<4;l++){
      int c = cB + l*4;
      Bs[c][iB] = V[((long)dlt*768 + k0 + c)*768 + it*64 + iB];
    }
    __syncthreads();
    #pragma unroll
    for (int kk=0;kk<16;kk++){
      float4 a4 = *(const float4*)(&As[kk][ty*4]);
      float4 b4 = *(const float4*)(&Bs[kk][tx*4]);
      float aa[4] = {a4.x,a4.y,a4.z,a4.w}, bb[4] = {b4.x,b4.y,b4.z,b4.w};
      #pragma unroll
      for (int jj=0;jj<4;jj++)
        #pragma unroll
        for (int ii=0;ii<4;ii++) acc[jj][ii] += aa[jj]*bb[ii];
    }
  }
  #pragma unroll
  for (int jj=0;jj<4;jj++){
    long j = jt*64 + ty*4 + jj;
    #pragma unroll
    for (int ii=0;ii<4;ii++){
      int i = it*64 + tx*4 + ii;
      wt[j*5376 + dlt*768 + i] = f2b(acc[jj][ii]);
    }
  }
}

// ---------------- beff ----------------
__global__ void k_beff(const float* __restrict__ wxrz, const float* __restrict__ wxn,
                       const float* __restrict__ bxrz, const float* __restrict__ bxn,
                       const float* __restrict__ cb3, const float* __restrict__ cb5,
                       const float* __restrict__ cb7, float* __restrict__ beff){
  int j = blockIdx.x*blockDim.x + threadIdx.x;
  if (j >= 1152) return;
  const float* row = (j < 768) ? (wxrz + (long)j*768) : (wxn + (long)(j-768)*768);
  float s = (j < 768) ? bxrz[j] : bxn[j-768];
  for (int c=0;c<768;c++){
    float cb = (c<256) ? cb3[c] : (c<512) ? cb5[c-256] : cb7[c-512];
    s += row[c]*cb;
  }
  beff[j] = s;
}

// ---------------- frag-pack Whrz: [slice8][nt3][kind r/z][kt12][lane64][8] ----------------
__global__ void k_pack_wrzf(const float* __restrict__ whrz, u16* __restrict__ wf){
  int idx = blockIdx.x*blockDim.x + threadIdx.x;
  if (idx >= 8*3*2*12*512) return;
  int j = idx & 7; int t1 = idx >> 3;
  int l = t1 & 63;  int t2 = t1 >> 6;
  int kt = t2 % 12; int t3 = t2 / 12;
  int kind = t3 & 1; int t4 = t3 >> 1;
  int nt = t4 % 3;  int sl = t4 / 3;
  int u = sl*48 + nt*16 + (l & 15);
  int k = kt*32 + (l >> 4)*8 + j;
  wf[idx] = f2b(whrz[(long)(kind*384 + u)*384 + k]);
}

// ---------------- frag-pack Whn hi/lo: [slice8][nt3][hi/lo][kt12][lane64][8] ----------------
__global__ void k_pack_wnf(const float* __restrict__ whn, u16* __restrict__ wf){
  int idx = blockIdx.x*blockDim.x + threadIdx.x;
  if (idx >= 8*3*2*12*512) return;
  int j = idx & 7; int t1 = idx >> 3;
  int l = t1 & 63;  int t2 = t1 >> 6;
  int kt = t2 % 12; int t3 = t2 / 12;
  int kind = t3 & 1; int t4 = t3 >> 1;
  int nt = t4 % 3;  int sl = t4 / 3;
  int u = sl*48 + nt*16 + (l & 15);
  int k = kt*32 + (l >> 4)*8 + j;
  float v = whn[(long)u*384 + k];
  u16 hi = f2b(v);
  wf[idx] = (kind == 0) ? hi : f2b(v - b2f(hi));
}

// ---------------- bf16 GEMM, m97 structure ----------------
template<bool F32OUT>
__global__ __launch_bounds__(256) void k_gemm(
    const u16* __restrict__ A, long a_sb, long a_ss,
    const u16* __restrict__ Bt, int K,
    const float* __restrict__ bias,
    void* __restrict__ C, int ldc, int col0)
{
  __shared__ __align__(16) u16 As[128*64];
  __shared__ __align__(16) u16 Bs[128*64];
  const int tid = threadIdx.x;
  const int wave = tid >> 6, lane = tid & 63;
  const int mt = blockIdx.x, nt = blockIdx.y;
  const long abase = (long)(mt >> 1)*a_sb + (long)((mt & 1)*128)*a_ss;
  const long bbase = (long)nt*128*K;
  const int lr = lane >> 3;
  const int lc = (lane & 7) * 8;
  const int wr = (wave >> 1)*64, wc = (wave & 1)*64;

  f32x4 acc[4][4];
  #pragma unroll
  for (int mi=0;mi<4;mi++)
    #pragma unroll
    for (int ni=0;ni<4;ni++) acc[mi][ni] = 0;

  for (int k0 = 0; k0 < K; k0 += 64){
    __syncthreads();
    #pragma unroll
    for (int a=0;a<4;a++){
      int q = wave*4 + a;
      const u16* srcA = A + abase + (long)(q*8 + lr)*a_ss + k0 + lc;
      __builtin_amdgcn_global_load_lds((const __attribute__((address_space(1))) void*)srcA,
                                       (__attribute__((address_space(3))) void*)(As + q*8*64), 16, 0, 0);
      const u16* srcB = Bt + bbase + (long)(q*8 + lr)*K + k0 + lc;
      __builtin_amdgcn_global_load_lds((const __attribute__((address_space(1))) void*)srcB,
                                       (__attribute__((address_space(3))) void*)(Bs + q*8*64), 16, 0, 0);
    }
    __syncthreads();
    #pragma unroll
    for (int kk=0;kk<2;kk++){
      const int kb = kk*32 + (lane >> 4)*8;
      bf16x8 af[4], bfr[4];
      #pragma unroll
      for (int mi=0;mi<4;mi++)
        af[mi] = *(const bf16x8*)(As + (wr + mi*16 + (lane & 15))*64 + kb);
      #pragma unroll
      for (int ni=0;ni<4;ni++)
        bfr[ni] = *(const bf16x8*)(Bs + (wc + ni*16 + (lane & 15))*64 + kb);
      #pragma unroll
      for (int mi=0;mi<4;mi++)
        #pragma unroll
        for (int ni=0;ni<4;ni++)
          acc[mi][ni] = __builtin_amdgcn_mfma_f32_16x16x32_bf16(af[mi], bfr[ni], acc[mi][ni], 0, 0, 0);
    }
  }
  const int rbase = mt*128 + wr + ((lane >> 4) << 2);
  const int cbase = nt*128 + wc + (lane & 15);
  #pragma unroll
  for (int mi=0;mi<4;mi++){
    #pragma unroll
    for (int ni=0;ni<4;ni++){
      int col = cbase + ni*16;
      float bv = bias ? bias[col] : 0.0f;
      #pragma unroll
      for (int j=0;j<4;j++){
        int row = rbase + mi*16 + j;
        if (F32OUT) ((float*)C)[(long)row*ldc + col0 + col] = acc[mi][ni][j] + bv;
        else        ((u16*)C)[(long)row*ldc + col0 + col] = f2b(acc[mi][ni][j] + bv);
      }
    }
  }
}

// ---------------- row LN on f32 scores (in-place) ----------------
__global__ __launch_bounds__(192) void k_ln1(
    float* __restrict__ sc,
    const float* __restrict__ g1, const float* __restrict__ b1,
    const float* __restrict__ g2, const float* __restrict__ b2)
{
  long row = blockIdx.x;
  float* r = sc + row*1152;
  int t = threadIdx.x;
  __shared__ float red[3][4];
  float s0=0, q0=0, s1=0, q1=0;
  float4 va, vb;
  if (t < 144){
    va = *(const float4*)(r + t*8);
    vb = *(const float4*)(r + t*8 + 4);
    float a = va.x+va.y+va.z+va.w + vb.x+vb.y+vb.z+vb.w;
    float aq = va.x*va.x+va.y*va.y+va.z*va.z+va.w*va.w
             + vb.x*vb.x+vb.y*vb.y+vb.z*vb.z+vb.w*vb.w;
    if (t < 96){ s0 = a; q0 = aq; } else { s1 = a; q1 = aq; }
  }
  int lane = t & 63, wid = t >> 6;
  #pragma unroll
  for (int o=32;o>0;o>>=1){
    s0 += __shfl_down(s0,o); q0 += __shfl_down(q0,o);
    s1 += __shfl_down(s1,o); q1 += __shfl_down(q1,o);
  }
  if (lane == 0){ red[wid][0]=s0; red[wid][1]=q0; red[wid][2]=s1; red[wid][3]=q1; }
  __syncthreads();
  float S0 = red[0][0]+red[1][0]+red[2][0];
  float Q0 = red[0][1]+red[1][1]+red[2][1];
  float S1 = red[0][2]+red[1][2]+red[2][2];
  float Q1 = red[0][3]+red[1][3]+red[2][3];
  if (t < 144){
    float mu, rs; const float *g, *bb; int cb;
    if (t < 96){ mu = S0*(1.f/768.f); rs = rsqrtf(Q0*(1.f/768.f) - mu*mu + 1e-5f); g=g1; bb=b1; cb = t*8; }
    else       { mu = S1*(1.f/384.f); rs = rsqrtf(Q1*(1.f/384.f) - mu*mu + 1e-5f); g=g2; bb=b2; cb = (t-96)*8; }
    float o[8] = {va.x,va.y,va.z,va.w,vb.x,vb.y,vb.z,vb.w};
    #pragma unroll
    for (int j=0;j<8;j++) o[j] = (o[j] - mu)*rs*g[cb+j] + bb[cb+j];
    *(float4*)(r + t*8)     = make_float4(o[0],o[1],o[2],o[3]);
    *(float4*)(r + t*8 + 4) = make_float4(o[4],o[5],o[6],o[7]);
  }
}

// ---------------- BiGRU v6b: per-wave flags + 3-chain n-matvec ----------------
// 32 groups x 8 slices = 256 blocks. One exchange/step; P parity double-buffered.
// flags[g][48][32-pad]: one line per (slice,mv-wave); producer wave raises its own
// flag after in-wave vmcnt(0) drain (no publish-side block barrier).
__global__ __launch_bounds__(512, 2) void k_gru6(
    const float* __restrict__ a,        // (32768 x 1152) [r|z|n] f32, LN'd
    const u16* __restrict__ wrzf, const u16* __restrict__ wnf,
    const float* __restrict__ bhrz, const float* __restrict__ bhn,
    const float* __restrict__ g1, const float* __restrict__ b1,
    const float* __restrict__ g2, const float* __restrict__ b2,
    float* __restrict__ outr,           // (32768 x 768) [fwd|bwd] f32
    u32* __restrict__ Pb,               // [2][32][8][1152] f32-bits (biased pre-acts)
    u32* __restrict__ flags)            // [32][48][32-pad] u32 monotonic tags
{
  const int bid = blockIdx.x;
  const int g = bid & 31, slice = bid >> 5;
  const int dir = g >> 4, bbase = (g & 15) * 8;
  const int tid = threadIdx.x, lane = tid & 63, wid = tid >> 6;
  const int nt = wid >> 1, kind = wid & 1;
  const bool is_rz = (wid < 6) && (kind == 0);
  const bool is_n  = (wid < 6) && (kind == 1);
  const int lc = lane & 15, lg = lane >> 4;
  const int uo = slice*48 + nt*16 + lc;    // matvec output unit (mv waves)
  const int b = wid;                        // batch role (all 8 waves)

  __shared__ __align__(16) u16 hlds[12544];   // hi[16][392] rows0-7 live, lo at +6272
  __shared__ float h_f32[8*384];              // exact f32 h
  __shared__ u32 lds_pad[11264];              // 45KB pad -> 1 block/CU

  // pad keep-alive (runtime-unprovable guard)
  if (__hip_atomic_load(flags, __ATOMIC_RELAXED, __HIP_MEMORY_SCOPE_AGENT) == 0xdeadbeefu)
    lds_pad[tid] = tid;

  // persistent weights (slice-indexed, R5/R7/R9-verified packing)
  bf16x8 wA[12], wB[12];
  if (wid < 6){
    const u16* buf = (kind == 0) ? wrzf : wnf;
    const long b0  = ((((long)slice*3 + nt)*2 + 0)*12)*512;
    const long b1o = ((((long)slice*3 + nt)*2 + 1)*12)*512;
    #pragma unroll
    for (int kt=0; kt<12; kt++){
      wA[kt] = *(const bf16x8*)(buf + b0  + kt*512 + lane*8);
      wB[kt] = *(const bf16x8*)(buf + b1o + kt*512 + lane*8);
    }
  }
  float bias0=0, bias1=0;
  if (is_rz){ bias0 = bhrz[uo]; bias1 = bhrz[384+uo]; }
  if (is_n){  bias0 = bhn[uo]; }

  // gate params: lane owns units u = lane*6 .. lane*6+5 (all waves)
  float G1r[6],B1r[6],G1z[6],B1z[6],G2v[6],B2v[6];
  #pragma unroll
  for (int i=0;i<6;i++){
    int u = lane*6 + i;
    G1r[i]=g1[u]; B1r[i]=b1[u]; G1z[i]=g1[384+u]; B1z[i]=b1[384+u];
    G2v[i]=g2[u]; B2v[i]=b2[u];
  }

  for (int i = tid; i < 12544/2; i += 512) ((u32*)hlds)[i] = 0;
  for (int i = tid; i < 8*384;   i += 512) h_f32[i] = 0.f;
  __syncthreads();

  u32* fgrp = flags + (long)g*48*32;
  float hnv[6];
  long orow_prev = 0;
  bool have_out = false;

  for (int step=0; step<256; step++){
    const int s_t = dir ? (255-step) : step;
    const int bsel = step & 1;
    const u32 tag = (u32)(step + 1);
    const long orow = (long)(bbase + b)*256 + s_t;
    u32* Pg = Pb + (((long)bsel*32 + g)*8)*1152;

    // deferred outr write from previous step (drains under matvec+publish)
    if (have_out){
      float* op = outr + orow_prev*768 + dir*384;
      #pragma unroll
      for (int i=0;i<6;i++) op[lane*6+i] = hnv[i];
    }

    // a prefetch (HBM/L2 latency overlaps matvec)
    float aR[6], aZ[6], aN[6];
    {
      const float* arow = a + orow*1152;
      #pragma unroll
      for (int i=0;i<6;i++){
        int u = lane*6 + i;
        aR[i] = arow[u]; aZ[i] = arow[384+u]; aN[i] = arow[768+u];
      }
    }

    // ---- matvec (mv waves) + publish own 48 units' pre-acts + per-wave flag ----
    if (is_rz){
      f32x4 ar = {bias0,bias0,bias0,bias0}, az = {bias1,bias1,bias1,bias1};
      #pragma unroll
      for (int kt=0;kt<12;kt++){
        const bf16x8 av = *(const bf16x8*)(hlds + lc*392 + kt*32 + lg*8);
        ar = __builtin_amdgcn_mfma_f32_16x16x32_bf16(av, wA[kt], ar, 0,0,0);
        az = __builtin_amdgcn_mfma_f32_16x16x32_bf16(av, wB[kt], az, 0,0,0);
      }
      if (lg < 2){
        #pragma unroll
        for (int j=0;j<4;j++){
          int row = lg*4 + j;
          u32* pp = Pg + (long)row*1152;
          __hip_atomic_store(pp + uo,       __float_as_uint(ar[j]), __ATOMIC_RELAXED, __HIP_MEMORY_SCOPE_AGENT);
          __hip_atomic_store(pp + 384 + uo, __float_as_uint(az[j]), __ATOMIC_RELAXED, __HIP_MEMORY_SCOPE_AGENT);
        }
      }
      asm volatile("s_waitcnt vmcnt(0)" ::: "memory");   // this wave's P stores visible
      if (lane == 0)
        __hip_atomic_store(fgrp + (slice*6 + wid)*32, tag, __ATOMIC_RELAXED, __HIP_MEMORY_SCOPE_AGENT);
    } else if (is_n){
      f32x4 a0 = {bias0,bias0,bias0,bias0}, a1 = {0,0,0,0}, a2 = {0,0,0,0};
      #pragma unroll
      for (int kt=0;kt<12;kt++){
        const bf16x8 ah = *(const bf16x8*)(hlds +        lc*392 + kt*32 + lg*8);
        const bf16x8 al = *(const bf16x8*)(hlds + 6272 + lc*392 + kt*32 + lg*8);
        a0 = __builtin_amdgcn_mfma_f32_16x16x32_bf16(ah, wA[kt], a0, 0,0,0);
        a1 = __builtin_amdgcn_mfma_f32_16x16x32_bf16(al, wA[kt], a1, 0,0,0);
        a2 = __builtin_amdgcn_mfma_f32_16x16x32_bf16(ah, wB[kt], a2, 0,0,0);
      }
      if (lg < 2){
        #pragma unroll
        for (int j=0;j<4;j++){
          int row = lg*4 + j;
          float v = a0[j] + a1[j] + a2[j];
          __hip_atomic_store(Pg + (long)row*1152 + 768 + uo, __float_as_uint(v),
                             __ATOMIC_RELAXED, __HIP_MEMORY_SCOPE_AGENT);
        }
      }
      asm volatile("s_waitcnt vmcnt(0)" ::: "memory");
      if (lane == 0)
        __hip_atomic_store(fgrp + (slice*6 + wid)*32, tag, __ATOMIC_RELAXED, __HIP_MEMORY_SCOPE_AGENT);
    }

    // ---- per-wave poll: all 48 (slice, mv-wave) flags at tag ----
    {
      int ok;
      do {
        u32 v = tag;
        if (lane < 48) v = __hip_atomic_load(fgrp + lane*32, __ATOMIC_RELAXED, __HIP_MEMORY_SCOPE_AGENT);
        ok = __all((int)(v >= tag));
        if (!ok) __builtin_amdgcn_s_sleep(2);
      } while (!ok);
    }

    // ---- pull exactly this lane's gate columns (9 u64) + stats partials ----
    float vr[6], vz[6], vn[6];
    float s1=0,q1=0,s2=0,q2=0;
    {
      const u32* Pr = Pg + (long)b*1152;
      #pragma unroll
      for (int k=0;k<3;k++){
        u64 v = __hip_atomic_load((const u64*)(Pr + lane*6 + k*2), __ATOMIC_RELAXED, __HIP_MEMORY_SCOPE_AGENT);
        float f0 = __uint_as_float((u32)v), f1 = __uint_as_float((u32)(v>>32));
        vr[k*2] = f0; vr[k*2+1] = f1;
        s1 += f0 + f1; q1 += f0*f0 + f1*f1;
      }
      #pragma unroll
      for (int k=0;k<3;k++){
        u64 v = __hip_atomic_load((const u64*)(Pr + 384 + lane*6 + k*2), __ATOMIC_RELAXED, __HIP_MEMORY_SCOPE_AGENT);
        float f0 = __uint_as_float((u32)v), f1 = __uint_as_float((u32)(v>>32));
        vz[k*2] = f0; vz[k*2+1] = f1;
        s1 += f0 + f1; q1 += f0*f0 + f1*f1;
      }
      #pragma unroll
      for (int k=0;k<3;k++){
        u64 v = __hip_atomic_load((const u64*)(Pr + 768 + lane*6 + k*2), __ATOMIC_RELAXED, __HIP_MEMORY_SCOPE_AGENT);
        float f0 = __uint_as_float((u32)v), f1 = __uint_as_float((u32)(v>>32));
        vn[k*2] = f0; vn[k*2+1] = f1;
        s2 += f0 + f1; q2 += f0*f0 + f1*f1;
      }
    }
    #pragma unroll
    for (int m=1;m<64;m<<=1){
      s1 += __shfl_xor(s1,m); q1 += __shfl_xor(q1,m);
      s2 += __shfl_xor(s2,m); q2 += __shfl_xor(q2,m);
    }
    float mu1 = s1*(1.f/768.f), rs1 = rsqrtf(q1*(1.f/768.f) - mu1*mu1 + 1e-5f);
    float mu2 = s2*(1.f/384.f), rs2 = rsqrtf(q2*(1.f/384.f) - mu2*mu2 + 1e-5f);

    // ---- gates + h update (redundant across slices; bit-identical) ----
    #pragma unroll
    for (int i=0;i<6;i++){
      int u = lane*6 + i;
      float gr = 1.f/(1.f + __expf(-(aR[i] + (vr[i]-mu1)*rs1*G1r[i] + B1r[i])));
      float gz = 1.f/(1.f + __expf(-(aZ[i] + (vz[i]-mu1)*rs1*G1z[i] + B1z[i])));
      float nv = tanhf(aN[i] + gr*((vn[i]-mu2)*rs2*G2v[i] + B2v[i]));
      float hn = (1.f-gz)*nv + gz*h_f32[b*384 + u];
      h_f32[b*384 + u] = hn;
      u16 hi = f2b(hn);
      hlds[b*392 + u]        = hi;
      hlds[6272 + b*392 + u] = f2b(hn - b2f(hi));
      hnv[i] = hn;
    }
    orow_prev = orow;
    have_out = true;
    __syncthreads();   // hlds(t+1) ready for next matvec (covers whole block)
  }
  // final step's outr write
  {
    float* op = outr + orow_prev*768 + dir*384;
    #pragma unroll
    for (int i=0;i<6;i++) op[lane*6+i] = hnv[i];
  }
}

// ---------------- final LN over 768 (f32 in), f32 out ----------------
__global__ __launch_bounds__(128) void k_lnout(
    const float* __restrict__ hr, const float* __restrict__ g, const float* __restrict__ bb,
    float* __restrict__ out)
{
  long row = blockIdx.x;
  const float* r = hr + row*768;
  int t = threadIdx.x;
  __shared__ float red[2][2];
  float s=0, q=0;
  float4 va, vb;
  if (t < 96){
    va = *(const float4*)(r + t*8);
    vb = *(const float4*)(r + t*8 + 4);
    s = va.x+va.y+va.z+va.w + vb.x+vb.y+vb.z+vb.w;
    q = va.x*va.x+va.y*va.y+va.z*va.z+va.w*va.w
      + vb.x*vb.x+vb.y*vb.y+vb.z*vb.z+vb.w*vb.w;
  }
  int lane = t & 63, wid = t >> 6;
  #pragma unroll
  for (int o=32;o>0;o>>=1){ s += __shfl_down(s,o); q += __shfl_down(q,o); }
  if (lane == 0){ red[wid][0]=s; red[wid][1]=q; }
  __syncthreads();
  float S = red[0][0]+red[1][0], Q = red[0][1]+red[1][1];
  float mu = S*(1.f/768.f), rs = rsqrtf(Q*(1.f/768.f) - mu*mu + 1e-5f);
  if (t < 96){
    float* op = out + row*768 + t*8;
    float iv[8] = {va.x,va.y,va.z,va.w,vb.x,vb.y,vb.z,vb.w};
    #pragma unroll
    for (int j=0;j<8;j++) op[j] = (iv[j] - mu)*rs*g[t*8+j] + bb[t*8+j];
  }
}

extern "C" void kernel_launch(void* const* d_in, const int* in_sizes, int n_in,
                              void* d_out, int out_size, void* d_ws, size_t ws_size,
                              hipStream_t stream){
  const float* x     = (const float*)d_in[0];
  const float* cw3   = (const float*)d_in[1];
  const float* cb3   = (const float*)d_in[2];
  const float* cw5   = (const float*)d_in[3];
  const float* cb5   = (const float*)d_in[4];
  const float* cw7   = (const float*)d_in[5];
  const float* cb7   = (const float*)d_in[6];
  const float* wxrz  = (const float*)d_in[7];
  const float* bxrz  = (const float*)d_in[8];
  const float* whrz  = (const float*)d_in[9];
  const float* bhrz  = (const float*)d_in[10];
  const float* wxn   = (const float*)d_in[11];
  const float* bxn   = (const float*)d_in[12];
  const float* whn   = (const float*)d_in[13];
  const float* bhn   = (const float*)d_in[14];
  const float* lnx1g = (const float*)d_in[15];
  const float* lnx1b = (const float*)d_in[16];
  const float* lnh1g = (const float*)d_in[17];
  const float* lnh1b = (const float*)d_in[18];
  const float* lnx2g = (const float*)d_in[19];
  const float* lnx2b = (const float*)d_in[20];
  const float* lnh2g = (const float*)d_in[21];
  const float* lnh2b = (const float*)d_in[22];
  const float* lnog  = (const float*)d_in[23];
  const float* lnob  = (const float*)d_in[24];

  char* w = (char*)d_ws;
  auto alloc = [&](size_t bytes)->char*{ char* p = w; w += (bytes + 255) & ~(size_t)255; return p; };
  // persistent (live through k_gru6):
  float* sc   = (float*)alloc(32768L*1152*4);     // 151 MB scores -> a
  u16*  wrzf  = (u16*) alloc(8L*3*2*12*512*2);
  u16*  wnf   = (u16*) alloc(8L*3*2*12*512*2);
  u32*  Pbuf  = (u32*) alloc(2L*32*8*1152*4);     // 2.36 MB double-buffered pre-acts
  u32*  flags = (u32*) alloc(32L*48*32*4);        // 196 KB padded per-wave flags
  // transient (dead after main GEMM) — outr aliases:
  char* regionA = w;
  u16*  xp   = (u16*) alloc(128L*262*768*2);
  u16*  weff = (u16*) alloc(1152L*5376*2);
  float* V   = (float*)alloc(7L*768*768*4);
  float* beff= (float*)alloc(1152*4);
  float* outr = (float*)regionA;

  k_zero<<<(32*48*32 + 255)/256, 256, 0, stream>>>(flags, 32*48*32);

  k_pad_cast<<<12576, 256, 0, stream>>>(x, xp);
  k_build_v<<<16128, 256, 0, stream>>>(cw3, cw5, cw7, V);
  k_weff<<<dim3(12,18,7), 256, 0, stream>>>(wxrz, wxn, V, weff);
  k_beff<<<5, 256, 0, stream>>>(wxrz, wxn, bxrz, bxn, cb3, cb5, cb7, beff);
  k_pack_wrzf<<<1152, 256, 0, stream>>>(whrz, wrzf);
  k_pack_wnf<<<1152, 256, 0, stream>>>(whn, wnf);

  k_gemm<true><<<dim3(256,9), 256, 0, stream>>>(xp, 262L*768, 768, weff, 5376, beff, sc, 1152, 0);
  k_ln1<<<32768, 192, 0, stream>>>(sc, lnx1g, lnx1b, lnx2g, lnx2b);
  k_gru6<<<256, 512, 0, stream>>>(sc, wrzf, wnf, bhrz, bhn, lnh1g, lnh1b, lnh2g, lnh2b,
                                  outr, Pbuf, flags);
  k_lnout<<<32768, 128, 0, stream>>>(outr, lnog, lnob, (float*)d_out);
}

// Round 15
// 2203.612 us; speedup vs baseline: 1.4338x; 1.4338x over previous
//
#include <hip/hip_runtime.h>
#include <hip/hip_bf16.h>
#include <stdint.h>

typedef __attribute__((ext_vector_type(4))) float f32x4;
typedef __attribute__((ext_vector_type(8))) short bf16x8;
typedef __attribute__((ext_vector_type(8))) unsigned short us8;
typedef unsigned short u16;
typedef unsigned int u32;
typedef unsigned long long u64;

#define DEV static __device__ __forceinline__

DEV u16 f2b(float f){
  u32 u = __float_as_uint(f);
  u += 0x7fffu + ((u >> 16) & 1u);
  return (u16)(u >> 16);
}
DEV float b2f(u16 h){ return __uint_as_float(((u32)h) << 16); }

// ---------------- zero helper (re-runs every launch: replay-safe) ----------------
__global__ void k_zero(u32* __restrict__ p, int n){
  int i = blockIdx.x*blockDim.x + threadIdx.x;
  if (i < n) p[i] = 0;
}

// ---------------- pad & cast x ----------------
__global__ void k_pad_cast(const float* __restrict__ x, u16* __restrict__ xp){
  int i8 = blockIdx.x * blockDim.x + threadIdx.x;
  int d8 = i8 % 96; int rest = i8 / 96;
  int sp = rest % 262; int b = rest / 262;
  us8 o;
  int s = sp - 3;
  if (s >= 0 && s < 256){
    const float* src = x + ((long)(b*256 + s)*768 + d8*8);
    #pragma unroll
    for (int j=0;j<8;j++) o[j] = f2b(src[j]);
  } else {
    #pragma unroll
    for (int j=0;j<8;j++) o[j] = 0;
  }
  *(us8*)(xp + (long)i8*8) = o;
}

// ---------------- V[d][c][i] ----------------
__global__ void k_build_v(const float* __restrict__ cw3, const float* __restrict__ cw5,
                          const float* __restrict__ cw7, float* __restrict__ V){
  int idx = blockIdx.x * blockDim.x + threadIdx.x;
  if (idx >= 7*768*768) return;
  int d = idx / (768*768); int rem = idx - d*(768*768);
  int c = rem / 768; int i = rem - c*768;
  int dd = d - 3;
  float v = 0.f;
  if (c < 256){ int t = dd + 1; if (t >= 0 && t < 3) v = cw3[((long)c*768 + i)*3 + t]; }
  else if (c < 512){ int t = dd + 2; if (t >= 0 && t < 5) v = cw5[((long)(c-256)*768 + i)*5 + t]; }
  else { int t = dd + 3; v = cw7[((long)(c-512)*768 + i)*7 + t]; }
  V[idx] = v;
}

// ---------------- Weff (K-loop starts at first nonzero channel block per tap) ----------------
__global__ __launch_bounds__(256) void k_weff(
    const float* __restrict__ wxrz, const float* __restrict__ wxn,
    const float* __restrict__ V, u16* __restrict__ wt)
{
  __shared__ float As[16][64];
  __shared__ float Bs[16][64];
  const int t = threadIdx.x;
  const int it = blockIdx.x, jt = blockIdx.y, dlt = blockIdx.z;
  // V[dlt][c][*] == 0 for c < cstart (per-tap segment validity) -> skip, identical result
  const int add3 = (dlt >= 3) ? dlt - 3 : 3 - dlt;
  const int cstart = (add3 == 3) ? 512 : (add3 == 2) ? 256 : 0;
  const float* Arow = (jt < 12) ? (wxrz + (long)jt*64*768) : (wxn + (long)(jt-12)*64*768);
  const int tx = t & 15, ty = t >> 4;
  const int jA = t >> 2, cqA = (t & 3) * 4;
  const int iB = t & 63, cB = t >> 6;
  float acc[4][4] = {};
  for (int k0 = cstart; k0 < 768; k0 += 16){
    __syncthreads();
    float4 av = *(const float4*)(Arow + (long)jA*768 + k0 + cqA);
    As[cqA+0][jA] = av.x; As[cqA+1][jA] = av.y; As[cqA+2][jA] = av.z; As[cqA+3][jA] = av.w;
    #pragma unroll
    for (int l=0;l<4;l++){
      int c = cB + l*4;
      Bs[c][iB] = V[((long)dlt*768 + k0 + c)*768 + it*64 + iB];
    }
    __syncthreads();
    #pragma unroll
    for (int kk=0;kk<16;kk++){
      float4 a4 = *(const float4*)(&As[kk][ty*4]);
      float4 b4 = *(const float4*)(&Bs[kk][tx*4]);
      float aa[4] = {a4.x,a4.y,a4.z,a4.w}, bb[4] = {b4.x,b4.y,b4.z,b4.w};
      #pragma unroll
      for (int jj=0;jj<4;jj++)
        #pragma unroll
        for (int ii=0;ii<4;ii++) acc[jj][ii] += aa[jj]*bb[ii];
    }
  }
  #pragma unroll
  for (int jj=0;jj<4;jj++){
    long j = jt*64 + ty*4 + jj;
    #pragma unroll
    for (int ii=0;ii<4;ii++){
      int i = it*64 + tx*4 + ii;
      wt[j*5376 + dlt*768 + i] = f2b(acc[jj][ii]);
    }
  }
}

// ---------------- beff ----------------
__global__ void k_beff(const float* __restrict__ wxrz, const float* __restrict__ wxn,
                       const float* __restrict__ bxrz, const float* __restrict__ bxn,
                       const float* __restrict__ cb3, const float* __restrict__ cb5,
                       const float* __restrict__ cb7, float* __restrict__ beff){
  int j = blockIdx.x*blockDim.x + threadIdx.x;
  if (j >= 1152) return;
  const float* row = (j < 768) ? (wxrz + (long)j*768) : (wxn + (long)(j-768)*768);
  float s = (j < 768) ? bxrz[j] : bxn[j-768];
  for (int c=0;c<768;c++){
    float cb = (c<256) ? cb3[c] : (c<512) ? cb5[c-256] : cb7[c-512];
    s += row[c]*cb;
  }
  beff[j] = s;
}

// ---------------- frag-pack Whrz: [slice8][nt3][kind r/z][kt12][lane64][8] ----------------
__global__ void k_pack_wrzf(const float* __restrict__ whrz, u16* __restrict__ wf){
  int idx = blockIdx.x*blockDim.x + threadIdx.x;
  if (idx >= 8*3*2*12*512) return;
  int j = idx & 7; int t1 = idx >> 3;
  int l = t1 & 63;  int t2 = t1 >> 6;
  int kt = t2 % 12; int t3 = t2 / 12;
  int kind = t3 & 1; int t4 = t3 >> 1;
  int nt = t4 % 3;  int sl = t4 / 3;
  int u = sl*48 + nt*16 + (l & 15);
  int k = kt*32 + (l >> 4)*8 + j;
  wf[idx] = f2b(whrz[(long)(kind*384 + u)*384 + k]);
}

// ---------------- frag-pack Whn hi/lo: [slice8][nt3][hi/lo][kt12][lane64][8] ----------------
__global__ void k_pack_wnf(const float* __restrict__ whn, u16* __restrict__ wf){
  int idx = blockIdx.x*blockDim.x + threadIdx.x;
  if (idx >= 8*3*2*12*512) return;
  int j = idx & 7; int t1 = idx >> 3;
  int l = t1 & 63;  int t2 = t1 >> 6;
  int kt = t2 % 12; int t3 = t2 / 12;
  int kind = t3 & 1; int t4 = t3 >> 1;
  int nt = t4 % 3;  int sl = t4 / 3;
  int u = sl*48 + nt*16 + (l & 15);
  int k = kt*32 + (l >> 4)*8 + j;
  float v = whn[(long)u*384 + k];
  u16 hi = f2b(v);
  wf[idx] = (kind == 0) ? hi : f2b(v - b2f(hi));
}

// ---------------- bf16 GEMM, m97 structure ----------------
template<bool F32OUT>
__global__ __launch_bounds__(256) void k_gemm(
    const u16* __restrict__ A, long a_sb, long a_ss,
    const u16* __restrict__ Bt, int K,
    const float* __restrict__ bias,
    void* __restrict__ C, int ldc, int col0)
{
  __shared__ __align__(16) u16 As[128*64];
  __shared__ __align__(16) u16 Bs[128*64];
  const int tid = threadIdx.x;
  const int wave = tid >> 6, lane = tid & 63;
  const int mt = blockIdx.x, nt = blockIdx.y;
  const long abase = (long)(mt >> 1)*a_sb + (long)((mt & 1)*128)*a_ss;
  const long bbase = (long)nt*128*K;
  const int lr = lane >> 3;
  const int lc = (lane & 7) * 8;
  const int wr = (wave >> 1)*64, wc = (wave & 1)*64;

  f32x4 acc[4][4];
  #pragma unroll
  for (int mi=0;mi<4;mi++)
    #pragma unroll
    for (int ni=0;ni<4;ni++) acc[mi][ni] = 0;

  for (int k0 = 0; k0 < K; k0 += 64){
    __syncthreads();
    #pragma unroll
    for (int a=0;a<4;a++){
      int q = wave*4 + a;
      const u16* srcA = A + abase + (long)(q*8 + lr)*a_ss + k0 + lc;
      __builtin_amdgcn_global_load_lds((const __attribute__((address_space(1))) void*)srcA,
                                       (__attribute__((address_space(3))) void*)(As + q*8*64), 16, 0, 0);
      const u16* srcB = Bt + bbase + (long)(q*8 + lr)*K + k0 + lc;
      __builtin_amdgcn_global_load_lds((const __attribute__((address_space(1))) void*)srcB,
                                       (__attribute__((address_space(3))) void*)(Bs + q*8*64), 16, 0, 0);
    }
    __syncthreads();
    #pragma unroll
    for (int kk=0;kk<2;kk++){
      const int kb = kk*32 + (lane >> 4)*8;
      bf16x8 af[4], bfr[4];
      #pragma unroll
      for (int mi=0;mi<4;mi++)
        af[mi] = *(const bf16x8*)(As + (wr + mi*16 + (lane & 15))*64 + kb);
      #pragma unroll
      for (int ni=0;ni<4;ni++)
        bfr[ni] = *(const bf16x8*)(Bs + (wc + ni*16 + (lane & 15))*64 + kb);
      #pragma unroll
      for (int mi=0;mi<4;mi++)
        #pragma unroll
        for (int ni=0;ni<4;ni++)
          acc[mi][ni] = __builtin_amdgcn_mfma_f32_16x16x32_bf16(af[mi], bfr[ni], acc[mi][ni], 0, 0, 0);
    }
  }
  const int rbase = mt*128 + wr + ((lane >> 4) << 2);
  const int cbase = nt*128 + wc + (lane & 15);
  #pragma unroll
  for (int mi=0;mi<4;mi++){
    #pragma unroll
    for (int ni=0;ni<4;ni++){
      int col = cbase + ni*16;
      float bv = bias ? bias[col] : 0.0f;
      #pragma unroll
      for (int j=0;j<4;j++){
        int row = rbase + mi*16 + j;
        if (F32OUT) ((float*)C)[(long)row*ldc + col0 + col] = acc[mi][ni][j] + bv;
        else        ((u16*)C)[(long)row*ldc + col0 + col] = f2b(acc[mi][ni][j] + bv);
      }
    }
  }
}

// ---------------- row LN on f32 scores (in-place) ----------------
__global__ __launch_bounds__(192) void k_ln1(
    float* __restrict__ sc,
    const float* __restrict__ g1, const float* __restrict__ b1,
    const float* __restrict__ g2, const float* __restrict__ b2)
{
  long row = blockIdx.x;
  float* r = sc + row*1152;
  int t = threadIdx.x;
  __shared__ float red[3][4];
  float s0=0, q0=0, s1=0, q1=0;
  float4 va, vb;
  if (t < 144){
    va = *(const float4*)(r + t*8);
    vb = *(const float4*)(r + t*8 + 4);
    float a = va.x+va.y+va.z+va.w + vb.x+vb.y+vb.z+vb.w;
    float aq = va.x*va.x+va.y*va.y+va.z*va.z+va.w*va.w
             + vb.x*vb.x+vb.y*vb.y+vb.z*vb.z+vb.w*vb.w;
    if (t < 96){ s0 = a; q0 = aq; } else { s1 = a; q1 = aq; }
  }
  int lane = t & 63, wid = t >> 6;
  #pragma unroll
  for (int o=32;o>0;o>>=1){
    s0 += __shfl_down(s0,o); q0 += __shfl_down(q0,o);
    s1 += __shfl_down(s1,o); q1 += __shfl_down(q1,o);
  }
  if (lane == 0){ red[wid][0]=s0; red[wid][1]=q0; red[wid][2]=s1; red[wid][3]=q1; }
  __syncthreads();
  float S0 = red[0][0]+red[1][0]+red[2][0];
  float Q0 = red[0][1]+red[1][1]+red[2][1];
  float S1 = red[0][2]+red[1][2]+red[2][2];
  float Q1 = red[0][3]+red[1][3]+red[2][3];
  if (t < 144){
    float mu, rs; const float *g, *bb; int cb;
    if (t < 96){ mu = S0*(1.f/768.f); rs = rsqrtf(Q0*(1.f/768.f) - mu*mu + 1e-5f); g=g1; bb=b1; cb = t*8; }
    else       { mu = S1*(1.f/384.f); rs = rsqrtf(Q1*(1.f/384.f) - mu*mu + 1e-5f); g=g2; bb=b2; cb = (t-96)*8; }
    float o[8] = {va.x,va.y,va.z,va.w,vb.x,vb.y,vb.z,vb.w};
    #pragma unroll
    for (int j=0;j<8;j++) o[j] = (o[j] - mu)*rs*g[cb+j] + bb[cb+j];
    *(float4*)(r + t*8)     = make_float4(o[0],o[1],o[2],o[3]);
    *(float4*)(r + t*8 + 4) = make_float4(o[4],o[5],o[6],o[7]);
  }
}

// ---------------- BiGRU v6: ONE exchange/step. 32 groups x 8 slices = 256 blocks ----------------
// Each block pulls ALL 1152 pre-acts of its group's 8 batches, computes stats+gates
// redundantly, and keeps the full h vector in LDS (bit-identical across slices).
// P double-buffered by step parity -> WAR-free. 2 barriers + 1 poll + 1 pull per step.
__global__ __launch_bounds__(512, 2) void k_gru6(
    const float* __restrict__ a,        // (32768 x 1152) [r|z|n] f32, LN'd
    const u16* __restrict__ wrzf, const u16* __restrict__ wnf,
    const float* __restrict__ bhrz, const float* __restrict__ bhn,
    const float* __restrict__ g1, const float* __restrict__ b1,
    const float* __restrict__ g2, const float* __restrict__ b2,
    float* __restrict__ outr,           // (32768 x 768) [fwd|bwd] f32
    u32* __restrict__ Pb,               // [2][32][8][1152] f32-bits (biased pre-acts)
    u32* __restrict__ flags)            // [32][8][32-pad] u32 monotonic tags
{
  const int bid = blockIdx.x;
  const int g = bid & 31, slice = bid >> 5;
  const int dir = g >> 4, bbase = (g & 15) * 8;
  const int tid = threadIdx.x, lane = tid & 63, wid = tid >> 6;
  const int nt = wid >> 1, kind = wid & 1;
  const bool is_rz = (wid < 6) && (kind == 0);
  const bool is_n  = (wid < 6) && (kind == 1);
  const int lc = lane & 15, lg = lane >> 4;
  const int uo = slice*48 + nt*16 + lc;    // matvec output unit (mv waves)
  const int b = wid;                        // batch role (all 8 waves)

  __shared__ __align__(16) u16 hlds[12544];   // hi[16][392] rows0-7 live, lo at +6272
  __shared__ float h_f32[8*384];              // exact f32 h
  __shared__ u32 lds_pad[11264];              // 45KB pad -> 1 block/CU

  // pad keep-alive (runtime-unprovable guard)
  if (__hip_atomic_load(flags, __ATOMIC_RELAXED, __HIP_MEMORY_SCOPE_AGENT) == 0xdeadbeefu)
    lds_pad[tid] = tid;

  // persistent weights (slice-indexed, R5/R7/R9-verified packing)
  bf16x8 wA[12], wB[12];
  if (wid < 6){
    const u16* buf = (kind == 0) ? wrzf : wnf;
    const long b0  = ((((long)slice*3 + nt)*2 + 0)*12)*512;
    const long b1o = ((((long)slice*3 + nt)*2 + 1)*12)*512;
    #pragma unroll
    for (int kt=0; kt<12; kt++){
      wA[kt] = *(const bf16x8*)(buf + b0  + kt*512 + lane*8);
      wB[kt] = *(const bf16x8*)(buf + b1o + kt*512 + lane*8);
    }
  }
  float bias0=0, bias1=0;
  if (is_rz){ bias0 = bhrz[uo]; bias1 = bhrz[384+uo]; }
  if (is_n){  bias0 = bhn[uo]; }

  // gate params: lane owns units u = lane*6 .. lane*6+5 (all waves)
  float G1r[6],B1r[6],G1z[6],B1z[6],G2v[6],B2v[6];
  #pragma unroll
  for (int i=0;i<6;i++){
    int u = lane*6 + i;
    G1r[i]=g1[u]; B1r[i]=b1[u]; G1z[i]=g1[384+u]; B1z[i]=b1[384+u];
    G2v[i]=g2[u]; B2v[i]=b2[u];
  }

  for (int i = tid; i < 12544/2; i += 512) ((u32*)hlds)[i] = 0;
  for (int i = tid; i < 8*384;   i += 512) h_f32[i] = 0.f;
  __syncthreads();

  u32* fgrp = flags + (long)g*8*32;
  float hnv[6];
  long orow_prev = 0;
  bool have_out = false;

  for (int step=0; step<256; step++){
    const int s_t = dir ? (255-step) : step;
    const int bsel = step & 1;
    const u32 tag = (u32)(step + 1);
    const long orow = (long)(bbase + b)*256 + s_t;
    u32* Pg = Pb + (((long)bsel*32 + g)*8)*1152;

    // deferred outr write from previous step (drains under matvec+publish)
    if (have_out){
      float* op = outr + orow_prev*768 + dir*384;
      #pragma unroll
      for (int i=0;i<6;i++) op[lane*6+i] = hnv[i];
    }

    // a prefetch (HBM/L2 latency overlaps matvec)
    float aR[6], aZ[6], aN[6];
    {
      const float* arow = a + orow*1152;
      #pragma unroll
      for (int i=0;i<6;i++){
        int u = lane*6 + i;
        aR[i] = arow[u]; aZ[i] = arow[384+u]; aN[i] = arow[768+u];
      }
    }

    // ---- matvec (mv waves) + publish own 48 units' pre-acts ----
    if (is_rz){
      f32x4 ar = {bias0,bias0,bias0,bias0}, az = {bias1,bias1,bias1,bias1};
      #pragma unroll
      for (int kt=0;kt<12;kt++){
        const bf16x8 av = *(const bf16x8*)(hlds + lc*392 + kt*32 + lg*8);
        ar = __builtin_amdgcn_mfma_f32_16x16x32_bf16(av, wA[kt], ar, 0,0,0);
        az = __builtin_amdgcn_mfma_f32_16x16x32_bf16(av, wB[kt], az, 0,0,0);
      }
      if (lg < 2){
        #pragma unroll
        for (int j=0;j<4;j++){
          int row = lg*4 + j;
          u32* pp = Pg + (long)row*1152;
          __hip_atomic_store(pp + uo,       __float_as_uint(ar[j]), __ATOMIC_RELAXED, __HIP_MEMORY_SCOPE_AGENT);
          __hip_atomic_store(pp + 384 + uo, __float_as_uint(az[j]), __ATOMIC_RELAXED, __HIP_MEMORY_SCOPE_AGENT);
        }
      }
    } else if (is_n){
      f32x4 acc = {bias0,bias0,bias0,bias0};
      #pragma unroll
      for (int kt=0;kt<12;kt++){
        const bf16x8 ah = *(const bf16x8*)(hlds +        lc*392 + kt*32 + lg*8);
        const bf16x8 al = *(const bf16x8*)(hlds + 6272 + lc*392 + kt*32 + lg*8);
        acc = __builtin_amdgcn_mfma_f32_16x16x32_bf16(ah, wA[kt], acc, 0,0,0);
        acc = __builtin_amdgcn_mfma_f32_16x16x32_bf16(al, wA[kt], acc, 0,0,0);
        acc = __builtin_amdgcn_mfma_f32_16x16x32_bf16(ah, wB[kt], acc, 0,0,0);
      }
      if (lg < 2){
        #pragma unroll
        for (int j=0;j<4;j++){
          int row = lg*4 + j;
          u32* pp = Pg + (long)row*1152;
          __hip_atomic_store(pp + 768 + uo, __float_as_uint(acc[j]), __ATOMIC_RELAXED, __HIP_MEMORY_SCOPE_AGENT);
        }
      }
    }
    __syncthreads();   // all publishes drained (compiler vmcnt(0) before barrier)
    if (tid == 0)
      __hip_atomic_store(fgrp + slice*32, tag, __ATOMIC_RELAXED, __HIP_MEMORY_SCOPE_AGENT);

    // ---- per-wave poll: all 8 slices published ----
    {
      int ok;
      do {
        u32 v = tag;
        if (lane < 8) v = __hip_atomic_load(fgrp + lane*32, __ATOMIC_RELAXED, __HIP_MEMORY_SCOPE_AGENT);
        ok = __all((int)(v >= tag));
        if (!ok) __builtin_amdgcn_s_sleep(2);
      } while (!ok);
    }

    // ---- pull exactly this lane's gate columns (9 u64) + stats partials ----
    float vr[6], vz[6], vn[6];
    float s1=0,q1=0,s2=0,q2=0;
    {
      const u32* Pr = Pg + (long)b*1152;
      #pragma unroll
      for (int k=0;k<3;k++){
        u64 v = __hip_atomic_load((const u64*)(Pr + lane*6 + k*2), __ATOMIC_RELAXED, __HIP_MEMORY_SCOPE_AGENT);
        float f0 = __uint_as_float((u32)v), f1 = __uint_as_float((u32)(v>>32));
        vr[k*2] = f0; vr[k*2+1] = f1;
        s1 += f0 + f1; q1 += f0*f0 + f1*f1;
      }
      #pragma unroll
      for (int k=0;k<3;k++){
        u64 v = __hip_atomic_load((const u64*)(Pr + 384 + lane*6 + k*2), __ATOMIC_RELAXED, __HIP_MEMORY_SCOPE_AGENT);
        float f0 = __uint_as_float((u32)v), f1 = __uint_as_float((u32)(v>>32));
        vz[k*2] = f0; vz[k*2+1] = f1;
        s1 += f0 + f1; q1 += f0*f0 + f1*f1;
      }
      #pragma unroll
      for (int k=0;k<3;k++){
        u64 v = __hip_atomic_load((const u64*)(Pr + 768 + lane*6 + k*2), __ATOMIC_RELAXED, __HIP_MEMORY_SCOPE_AGENT);
        float f0 = __uint_as_float((u32)v), f1 = __uint_as_float((u32)(v>>32));
        vn[k*2] = f0; vn[k*2+1] = f1;
        s2 += f0 + f1; q2 += f0*f0 + f1*f1;
      }
    }
    #pragma unroll
    for (int m=1;m<64;m<<=1){
      s1 += __shfl_xor(s1,m); q1 += __shfl_xor(q1,m);
      s2 += __shfl_xor(s2,m); q2 += __shfl_xor(q2,m);
    }
    float mu1 = s1*(1.f/768.f), rs1 = rsqrtf(q1*(1.f/768.f) - mu1*mu1 + 1e-5f);
    float mu2 = s2*(1.f/384.f), rs2 = rsqrtf(q2*(1.f/384.f) - mu2*mu2 + 1e-5f);

    // ---- gates + h update (redundant across slices; bit-identical) ----
    #pragma unroll
    for (int i=0;i<6;i++){
      int u = lane*6 + i;
      float gr = 1.f/(1.f + __expf(-(aR[i] + (vr[i]-mu1)*rs1*G1r[i] + B1r[i])));
      float gz = 1.f/(1.f + __expf(-(aZ[i] + (vz[i]-mu1)*rs1*G1z[i] + B1z[i])));
      float nv = tanhf(aN[i] + gr*((vn[i]-mu2)*rs2*G2v[i] + B2v[i]));
      float hn = (1.f-gz)*nv + gz*h_f32[b*384 + u];
      h_f32[b*384 + u] = hn;
      u16 hi = f2b(hn);
      hlds[b*392 + u]        = hi;
      hlds[6272 + b*392 + u] = f2b(hn - b2f(hi));
      hnv[i] = hn;
    }
    orow_prev = orow;
    have_out = true;
    __syncthreads();   // hlds(t+1) ready for next matvec
  }
  // final step's outr write
  {
    float* op = outr + orow_prev*768 + dir*384;
    #pragma unroll
    for (int i=0;i<6;i++) op[lane*6+i] = hnv[i];
  }
}

// ---------------- final LN over 768 (f32 in), f32 out ----------------
__global__ __launch_bounds__(128) void k_lnout(
    const float* __restrict__ hr, const float* __restrict__ g, const float* __restrict__ bb,
    float* __restrict__ out)
{
  long row = blockIdx.x;
  const float* r = hr + row*768;
  int t = threadIdx.x;
  __shared__ float red[2][2];
  float s=0, q=0;
  float4 va, vb;
  if (t < 96){
    va = *(const float4*)(r + t*8);
    vb = *(const float4*)(r + t*8 + 4);
    s = va.x+va.y+va.z+va.w + vb.x+vb.y+vb.z+vb.w;
    q = va.x*va.x+va.y*va.y+va.z*va.z+va.w*va.w
      + vb.x*vb.x+vb.y*vb.y+vb.z*vb.z+vb.w*vb.w;
  }
  int lane = t & 63, wid = t >> 6;
  #pragma unroll
  for (int o=32;o>0;o>>=1){ s += __shfl_down(s,o); q += __shfl_down(q,o); }
  if (lane == 0){ red[wid][0]=s; red[wid][1]=q; }
  __syncthreads();
  float S = red[0][0]+red[1][0], Q = red[0][1]+red[1][1];
  float mu = S*(1.f/768.f), rs = rsqrtf(Q*(1.f/768.f) - mu*mu + 1e-5f);
  if (t < 96){
    float* op = out + row*768 + t*8;
    float iv[8] = {va.x,va.y,va.z,va.w,vb.x,vb.y,vb.z,vb.w};
    #pragma unroll
    for (int j=0;j<8;j++) op[j] = (iv[j] - mu)*rs*g[t*8+j] + bb[t*8+j];
  }
}

extern "C" void kernel_launch(void* const* d_in, const int* in_sizes, int n_in,
                              void* d_out, int out_size, void* d_ws, size_t ws_size,
                              hipStream_t stream){
  const float* x     = (const float*)d_in[0];
  const float* cw3   = (const float*)d_in[1];
  const float* cb3   = (const float*)d_in[2];
  const float* cw5   = (const float*)d_in[3];
  const float* cb5   = (const float*)d_in[4];
  const float* cw7   = (const float*)d_in[5];
  const float* cb7   = (const float*)d_in[6];
  const float* wxrz  = (const float*)d_in[7];
  const float* bxrz  = (const float*)d_in[8];
  const float* whrz  = (const float*)d_in[9];
  const float* bhrz  = (const float*)d_in[10];
  const float* wxn   = (const float*)d_in[11];
  const float* bxn   = (const float*)d_in[12];
  const float* whn   = (const float*)d_in[13];
  const float* bhn   = (const float*)d_in[14];
  const float* lnx1g = (const float*)d_in[15];
  const float* lnx1b = (const float*)d_in[16];
  const float* lnh1g = (const float*)d_in[17];
  const float* lnh1b = (const float*)d_in[18];
  const float* lnx2g = (const float*)d_in[19];
  const float* lnx2b = (const float*)d_in[20];
  const float* lnh2g = (const float*)d_in[21];
  const float* lnh2b = (const float*)d_in[22];
  const float* lnog  = (const float*)d_in[23];
  const float* lnob  = (const float*)d_in[24];

  char* w = (char*)d_ws;
  auto alloc = [&](size_t bytes)->char*{ char* p = w; w += (bytes + 255) & ~(size_t)255; return p; };
  // persistent (live through k_gru6):
  float* sc   = (float*)alloc(32768L*1152*4);     // 151 MB scores -> a
  u16*  wrzf  = (u16*) alloc(8L*3*2*12*512*2);
  u16*  wnf   = (u16*) alloc(8L*3*2*12*512*2);
  u32*  Pbuf  = (u32*) alloc(2L*32*8*1152*4);     // 2.36 MB double-buffered pre-acts
  u32*  flags = (u32*) alloc(32L*8*32*4);         // 32 KB padded flags
  // transient (dead after main GEMM) — outr aliases:
  char* regionA = w;
  u16*  xp   = (u16*) alloc(128L*262*768*2);
  u16*  weff = (u16*) alloc(1152L*5376*2);
  float* V   = (float*)alloc(7L*768*768*4);
  float* beff= (float*)alloc(1152*4);
  float* outr = (float*)regionA;

  k_zero<<<32, 256, 0, stream>>>(flags, 32*8*32);

  k_pad_cast<<<12576, 256, 0, stream>>>(x, xp);
  k_build_v<<<16128, 256, 0, stream>>>(cw3, cw5, cw7, V);
  k_weff<<<dim3(12,18,7), 256, 0, stream>>>(wxrz, wxn, V, weff);
  k_beff<<<5, 256, 0, stream>>>(wxrz, wxn, bxrz, bxn, cb3, cb5, cb7, beff);
  k_pack_wrzf<<<1152, 256, 0, stream>>>(whrz, wrzf);
  k_pack_wnf<<<1152, 256, 0, stream>>>(whn, wnf);

  k_gemm<true><<<dim3(256,9), 256, 0, stream>>>(xp, 262L*768, 768, weff, 5376, beff, sc, 1152, 0);
  k_ln1<<<32768, 192, 0, stream>>>(sc, lnx1g, lnx1b, lnx2g, lnx2b);
  k_gru6<<<256, 512, 0, stream>>>(sc, wrzf, wnf, bhrz, bhn, lnh1g, lnh1b, lnh2g, lnh2b,
                                  outr, Pbuf, flags);
  k_lnout<<<32768, 128, 0, stream>>>(outr, lnog, lnob, (float*)d_out);
}